// Round 1
// baseline (493.385 us; speedup 1.0000x reference)
//
#include <hip/hip_runtime.h>

#define BB   4
#define CIN  64
#define HH   128
#define WW   128
#define COUT 64
#define DG   8
#define CG   8
#define KK   9
#define HO   128
#define WO   128
#define PAD  1

// One thread per output pixel (b,ho,wo); acc[COUT] in VGPRs.
// Weights for the current deformable group staged in LDS as [kk][o][c].
__global__ __launch_bounds__(256, 1) void dcn_fused(
    const float* __restrict__ x, const float* __restrict__ off,
    const float* __restrict__ wgt, const float* __restrict__ bias,
    float* __restrict__ out)
{
    __shared__ float sw[KK * COUT * CG]; // [kk][o][c]  18432 B

    const int tid = threadIdx.x;
    const int pix = blockIdx.x * 256 + tid;     // [0, B*HO*WO)
    const int b   = pix >> 14;                  // / (HO*WO)
    const int rem = pix & 16383;
    const int ho  = rem >> 7;                   // / WO
    const int wo  = rem & 127;

    float acc[COUT];
#pragma unroll
    for (int o = 0; o < COUT; ++o) acc[o] = 0.f;

    const float fy0 = (float)(ho - PAD);
    const float fx0 = (float)(wo - PAD);

    for (int g = 0; g < DG; ++g) {
        __syncthreads();   // protect previous iteration's LDS reads
        for (int i = tid; i < KK * COUT * CG; i += 256) {
            int kk = i / (COUT * CG);
            int r  = i - kk * (COUT * CG);
            int o  = r >> 3;
            int c  = r & 7;
            sw[i] = wgt[(o * CIN + g * CG + c) * KK + kk];
        }
        __syncthreads();

        const float* xg   = x + ((size_t)(b * DG + g) * CG) * (HH * WW);
        const float* offg = off + (((size_t)(b * DG + g) * KK) * 2) * (HO * WO) + rem;

        for (int kk = 0; kk < KK; ++kk) {
            float dy = offg[(kk * 2 + 0) * (HO * WO)];
            float dx = offg[(kk * 2 + 1) * (HO * WO)];
            float py = fy0 + (float)(kk / 3) + dy;
            float px = fx0 + (float)(kk % 3) + dx;
            float y0f = floorf(py), x0f = floorf(px);
            int y0 = (int)y0f, x0 = (int)x0f;
            float ly = py - y0f, lx = px - x0f;
            float hy = 1.f - ly, hx = 1.f - lx;
            float w00 = hy * hx, w01 = hy * lx, w10 = ly * hx, w11 = ly * lx;
            int y1 = y0 + 1, x1 = x0 + 1;
            bool vy0 = (unsigned)y0 < (unsigned)HH, vy1 = (unsigned)y1 < (unsigned)HH;
            bool vx0 = (unsigned)x0 < (unsigned)WW, vx1 = (unsigned)x1 < (unsigned)WW;
            if (!(vy0 && vx0)) w00 = 0.f;
            if (!(vy0 && vx1)) w01 = 0.f;
            if (!(vy1 && vx0)) w10 = 0.f;
            if (!(vy1 && vx1)) w11 = 0.f;
            int y0c = min(max(y0, 0), HH - 1), y1c = min(max(y1, 0), HH - 1);
            int x0c = min(max(x0, 0), WW - 1), x1c = min(max(x1, 0), WW - 1);
            int i00 = y0c * WW + x0c, i01 = y0c * WW + x1c;
            int i10 = y1c * WW + x0c, i11 = y1c * WW + x1c;

            float v[CG];
#pragma unroll
            for (int c = 0; c < CG; ++c) {
                const float* xc = xg + c * (HH * WW);
                v[c] = w00 * xc[i00] + w01 * xc[i01] + w10 * xc[i10] + w11 * xc[i11];
            }

            const float4* swk = (const float4*)&sw[kk * (COUT * CG)];
#pragma unroll
            for (int o = 0; o < COUT; ++o) {
                float4 a  = swk[o * 2 + 0];
                float4 bq = swk[o * 2 + 1];
                acc[o] += a.x  * v[0] + a.y  * v[1] + a.z  * v[2] + a.w  * v[3]
                        + bq.x * v[4] + bq.y * v[5] + bq.z * v[6] + bq.w * v[7];
            }
        }
    }

    const size_t obase = ((size_t)b * COUT) * (HO * WO) + rem;
#pragma unroll
    for (int o = 0; o < COUT; ++o) {
        out[obase + (size_t)o * (HO * WO)] = acc[o] + bias[o];
    }
}

extern "C" void kernel_launch(void* const* d_in, const int* in_sizes, int n_in,
                              void* d_out, int out_size, void* d_ws, size_t ws_size,
                              hipStream_t stream) {
    const float* x    = (const float*)d_in[0];
    const float* off  = (const float*)d_in[1];
    const float* wgt  = (const float*)d_in[2];
    const float* bias = (const float*)d_in[3];
    float* out = (float*)d_out;

    const int total_pix = BB * HO * WO;          // 65536
    dcn_fused<<<dim3(total_pix / 256), dim3(256), 0, stream>>>(x, off, wgt, bias, out);
}

// Round 2
// 202.806 us; speedup vs baseline: 2.4328x; 2.4328x over previous
//
#include <hip/hip_runtime.h>

#define BB    4
#define CINT  64
#define HH    128
#define WW    128
#define COUT  64
#define DGN   8
#define CG    8
#define KKN   9
#define HO    128
#define WO    128
#define HOWO  16384
#define NCHUNK 18          // K = 576 = 18 * 32

typedef __bf16 bf16x8 __attribute__((ext_vector_type(8)));
typedef float  f32x4  __attribute__((ext_vector_type(4)));

static __device__ __forceinline__ ushort f2bf(float f) {
    unsigned u = __builtin_bit_cast(unsigned, f);
    u += 0x7fffu + ((u >> 16) & 1u);      // round-to-nearest-even
    return (ushort)(u >> 16);
}

// Swizzle weights into exact MFMA A-fragment order, bf16:
// layout [chunk(18)][mtile(4)][lane(64)] x 8 bf16 (16B per entry).
// A[m=lane&15][k=(lane>>4)*8+j], o = mtile*16+m, k = chunk*32 + (lane>>4)*8 + j,
// K order: k = (g*9+kk)*8 + c.
__global__ void prep_w(const float* __restrict__ wgt, uint4* __restrict__ wout) {
    int i = blockIdx.x * 256 + threadIdx.x;     // 0..4607
    if (i >= NCHUNK * 4 * 64) return;
    int lane = i & 63;
    int mt   = (i >> 6) & 3;
    int kt   = i >> 8;
    int m = lane & 15, quad = lane >> 4;
    int o = mt * 16 + m;
    union { ushort u[8]; uint4 v; } pk;
#pragma unroll
    for (int j = 0; j < 8; ++j) {
        int k   = kt * 32 + quad * 8 + j;
        int gkk = k >> 3, c = k & 7;
        int g   = gkk / 9, kk = gkk - 9 * g;
        pk.u[j] = f2bf(wgt[(o * CINT + g * CG + c) * KKN + kk]);
    }
    wout[i] = pk.v;
}

// Block: 64 pixels, 256 threads (4 waves). Wave w computes out[0:64][px w*16..w*16+16)
// via 4 MFMA m-tiles. col chunks (32 K-values) double-buffered in LDS.
__global__ __launch_bounds__(256, 4) void dcn_mfma(
    const float* __restrict__ x, const float* __restrict__ off,
    const uint4* __restrict__ wq, const float* __restrict__ bias,
    float* __restrict__ out)
{
    __shared__ __align__(16) ushort col[2][64][40];   // 40 = 32 + 8 pad (bank-safe)
    __shared__ float sbias[COUT];

    const int tid  = threadIdx.x;
    const int wave = tid >> 6;
    const int lane = tid & 63;
    const int px   = tid & 63;     // producer pixel within tile
    const int p    = wave;         // producer quarter: gkk = ch*4 + p

    const int pix_base = blockIdx.x * 64;
    const int b        = pix_base >> 14;
    const int rem_base = pix_base & 16383;
    const int rem      = rem_base + px;
    const int ho = rem >> 7, wo = rem & 127;
    const float fy0 = (float)(ho - 1);
    const float fx0 = (float)(wo - 1);

    if (tid < COUT) sbias[tid] = bias[tid];

    f32x4 acc[4];
#pragma unroll
    for (int mt = 0; mt < 4; ++mt) acc[mt] = (f32x4){0.f, 0.f, 0.f, 0.f};

    auto produce = [&](int ch) {
        int gkk = ch * 4 + p;                 // 0..71, wave-uniform
        int g = gkk / 9, kk = gkk - 9 * g;
        const float* offp = off + ((size_t)((b * DGN + g) * KKN + kk) * 2) * HOWO + rem;
        float dy = offp[0];
        float dx = offp[HOWO];
        float py  = fy0 + (float)(kk / 3) + dy;
        float pxx = fx0 + (float)(kk - (kk / 3) * 3) + dx;
        float y0f = floorf(py), x0f = floorf(pxx);
        int y0 = (int)y0f, x0 = (int)x0f;
        float ly = py - y0f, lx = pxx - x0f;
        float hy = 1.f - ly, hx = 1.f - lx;
        float w00 = hy * hx, w01 = hy * lx, w10 = ly * hx, w11 = ly * lx;
        int y1 = y0 + 1, x1 = x0 + 1;
        bool vy0 = (unsigned)y0 < (unsigned)HH, vy1 = (unsigned)y1 < (unsigned)HH;
        bool vx0 = (unsigned)x0 < (unsigned)WW, vx1 = (unsigned)x1 < (unsigned)WW;
        if (!(vy0 && vx0)) w00 = 0.f;
        if (!(vy0 && vx1)) w01 = 0.f;
        if (!(vy1 && vx0)) w10 = 0.f;
        if (!(vy1 && vx1)) w11 = 0.f;
        int y0c = min(max(y0, 0), HH - 1), y1c = min(max(y1, 0), HH - 1);
        int x0c = min(max(x0, 0), WW - 1), x1c = min(max(x1, 0), WW - 1);
        int i00 = y0c * WW + x0c, i01 = y0c * WW + x1c;
        int i10 = y1c * WW + x0c, i11 = y1c * WW + x1c;
        const float* xg = x + (size_t)((b * DGN + g) * CG) * (HH * WW);
        union { ushort u[8]; uint4 v; } pk;
#pragma unroll
        for (int c = 0; c < CG; ++c) {
            const float* xc = xg + c * (HH * WW);
            float v = w00 * xc[i00] + w01 * xc[i01] + w10 * xc[i10] + w11 * xc[i11];
            pk.u[c] = f2bf(v);
        }
        *(uint4*)&col[ch & 1][px][p * 8] = pk.v;
    };

    produce(0);

    const int brow  = wave * 16 + (lane & 15);   // pixel for b-frag
    const int bkoff = (lane >> 4) * 8;           // k offset within chunk

    for (int ch = 0; ch < NCHUNK; ++ch) {
        __syncthreads();
        bf16x8 bfrag = *(const bf16x8*)&col[ch & 1][brow][bkoff];
#pragma unroll
        for (int mt = 0; mt < 4; ++mt) {
            bf16x8 afrag = __builtin_bit_cast(bf16x8, wq[(ch * 4 + mt) * 64 + lane]);
            acc[mt] = __builtin_amdgcn_mfma_f32_16x16x32_bf16(afrag, bfrag, acc[mt], 0, 0, 0);
        }
        if (ch + 1 < NCHUNK) produce(ch + 1);
    }

    // C/D layout: col = lane&15 (pixel), row = (lane>>4)*4 + reg (out channel)
    const int n = lane & 15, quad = lane >> 4;
    const int rem_out = rem_base + wave * 16 + n;
    float* outp = out + (size_t)b * COUT * HOWO + rem_out;
#pragma unroll
    for (int mt = 0; mt < 4; ++mt) {
#pragma unroll
        for (int r = 0; r < 4; ++r) {
            int o = mt * 16 + quad * 4 + r;
            outp[(size_t)o * HOWO] = acc[mt][r] + sbias[o];
        }
    }
}

extern "C" void kernel_launch(void* const* d_in, const int* in_sizes, int n_in,
                              void* d_out, int out_size, void* d_ws, size_t ws_size,
                              hipStream_t stream) {
    const float* x    = (const float*)d_in[0];
    const float* off  = (const float*)d_in[1];
    const float* wgt  = (const float*)d_in[2];
    const float* bias = (const float*)d_in[3];
    float* out = (float*)d_out;
    uint4* wq  = (uint4*)d_ws;    // 18*4*64*16 = 73728 bytes

    prep_w<<<dim3(NCHUNK), dim3(256), 0, stream>>>(wgt, wq);
    dcn_mfma<<<dim3(BB * HO * WO / 64), dim3(256), 0, stream>>>(x, off, wq, bias, out);
}

// Round 3
// 120.840 us; speedup vs baseline: 4.0830x; 1.6783x over previous
//
#include <hip/hip_runtime.h>

#define BB    4
#define CINT  64
#define HH    128
#define WW    128
#define COUT  64
#define DGN   8
#define CG    8
#define KKN   9
#define HO    128
#define WO    128
#define HOWO  16384
#define HWSZ  (HH * WW)
#define NCHUNK 18          // K = 576 = 18 * 32

typedef __bf16 bf16x8 __attribute__((ext_vector_type(8)));
typedef float  f32x4  __attribute__((ext_vector_type(4)));

static __device__ __forceinline__ ushort f2bf(float f) {
    unsigned u = __builtin_bit_cast(unsigned, f);
    u += 0x7fffu + ((u >> 16) & 1u);      // round-to-nearest-even
    return (ushort)(u >> 16);
}
static __device__ __forceinline__ float bf2f(ushort u) {
    return __builtin_bit_cast(float, (unsigned)u << 16);
}

// ---- prep 1: weights into exact MFMA A-fragment order, bf16.
// layout [chunk(18)][mtile(4)][lane(64)] x 8 bf16 (16B per entry).
// A[m=lane&15][k=(lane>>4)*8+j], o = mtile*16+m, K order k = (g*9+kk)*8 + c.
__global__ void prep_w(const float* __restrict__ wgt, uint4* __restrict__ wout) {
    int i = blockIdx.x * 256 + threadIdx.x;     // 0..4607
    if (i >= NCHUNK * 4 * 64) return;
    int lane = i & 63;
    int mt   = (i >> 6) & 3;
    int kt   = i >> 8;
    int m = lane & 15, quad = lane >> 4;
    int o = mt * 16 + m;
    union { ushort u[8]; uint4 v; } pk;
#pragma unroll
    for (int j = 0; j < 8; ++j) {
        int k   = kt * 32 + quad * 8 + j;
        int gkk = k >> 3, c = k & 7;
        int g   = gkk / 9, kk = gkk - 9 * g;
        pk.u[j] = f2bf(wgt[(o * CINT + g * CG + c) * KKN + kk]);
    }
    wout[i] = pk.v;
}

// ---- prep 2: x [B, DG*CG, H, W] f32  ->  xh [B, DG, H, W, CG] bf16 (16B granules)
__global__ void prep_x(const float* __restrict__ x, uint4* __restrict__ xh) {
    int i  = blockIdx.x * 256 + threadIdx.x;    // over B*DG*H*W = 524288
    int yx = i & (HWSZ - 1);
    int bg = i >> 14;
    const float* xp = x + (size_t)bg * CG * HWSZ + yx;
    union { ushort u[8]; uint4 v; } pk;
#pragma unroll
    for (int c = 0; c < CG; ++c) pk.u[c] = f2bf(xp[c * HWSZ]);
    xh[i] = pk.v;
}

// ---- main: block = 64 pixels, 4 waves; wave w consumes pixels w*16..+16,
// produces col-quarter gkk = ch*4 + w. Double-buffered 32-K chunks in LDS.
__global__ __launch_bounds__(256, 6) void dcn_mfma(
    const uint4* __restrict__ xh, const float* __restrict__ off,
    const uint4* __restrict__ wq, const float* __restrict__ bias,
    float* __restrict__ out)
{
    __shared__ __align__(16) ushort col[2][64][40];   // 40 = 32 + 8 pad
    __shared__ float sbias[COUT];

    const int tid  = threadIdx.x;
    const int wave = tid >> 6;
    const int lane = tid & 63;
    const int px   = tid & 63;     // producer pixel within tile
    const int p    = wave;         // producer quarter

    const int pix_base = blockIdx.x * 64;
    const int b        = pix_base >> 14;
    const int rem_base = pix_base & 16383;
    const int rem      = rem_base + px;
    const int ho = rem >> 7, wo = rem & 127;
    const float fy0 = (float)(ho - 1);
    const float fx0 = (float)(wo - 1);

    if (tid < COUT) sbias[tid] = bias[tid];

    f32x4 acc[4];
#pragma unroll
    for (int mt = 0; mt < 4; ++mt) acc[mt] = (f32x4){0.f, 0.f, 0.f, 0.f};

    auto produce = [&](int ch) {
        int gkk = ch * 4 + p;                 // wave-uniform
        int g = gkk / 9, kk = gkk - 9 * g;
        const float* offp = off + ((size_t)((b * DGN + g) * KKN + kk) * 2) * HOWO + rem;
        float dy = offp[0];
        float dx = offp[HOWO];
        float py  = fy0 + (float)(kk / 3) + dy;
        float pxx = fx0 + (float)(kk - (kk / 3) * 3) + dx;
        float y0f = floorf(py), x0f = floorf(pxx);
        int y0 = (int)y0f, x0 = (int)x0f;
        float ly = py - y0f, lx = pxx - x0f;
        float hy = 1.f - ly, hx = 1.f - lx;
        float w00 = hy * hx, w01 = hy * lx, w10 = ly * hx, w11 = ly * lx;
        int y1 = y0 + 1, x1 = x0 + 1;
        bool vy0 = (unsigned)y0 < (unsigned)HH, vy1 = (unsigned)y1 < (unsigned)HH;
        bool vx0 = (unsigned)x0 < (unsigned)WW, vx1 = (unsigned)x1 < (unsigned)WW;
        if (!(vy0 && vx0)) w00 = 0.f;
        if (!(vy0 && vx1)) w01 = 0.f;
        if (!(vy1 && vx0)) w10 = 0.f;
        if (!(vy1 && vx1)) w11 = 0.f;
        int y0c = min(max(y0, 0), HH - 1), y1c = min(max(y1, 0), HH - 1);
        int x0c = min(max(x0, 0), WW - 1), x1c = min(max(x1, 0), WW - 1);
        const uint4* xgp = xh + (size_t)(b * DGN + g) * HWSZ;
        uint4 q00 = xgp[y0c * WW + x0c];
        uint4 q01 = xgp[y0c * WW + x1c];
        uint4 q10 = xgp[y1c * WW + x0c];
        uint4 q11 = xgp[y1c * WW + x1c];
        const ushort* u00 = (const ushort*)&q00;
        const ushort* u01 = (const ushort*)&q01;
        const ushort* u10 = (const ushort*)&q10;
        const ushort* u11 = (const ushort*)&q11;
        union { ushort u[8]; uint4 v; } pk;
#pragma unroll
        for (int c = 0; c < CG; ++c) {
            float v = w00 * bf2f(u00[c]) + w01 * bf2f(u01[c])
                    + w10 * bf2f(u10[c]) + w11 * bf2f(u11[c]);
            pk.u[c] = f2bf(v);
        }
        *(uint4*)&col[ch & 1][px][p * 8] = pk.v;
    };

    produce(0);

    const int brow  = wave * 16 + (lane & 15);   // pixel for b-frag
    const int bkoff = (lane >> 4) * 8;           // k offset within chunk

    for (int ch = 0; ch < NCHUNK; ++ch) {
        __syncthreads();
        bf16x8 bfrag = *(const bf16x8*)&col[ch & 1][brow][bkoff];
#pragma unroll
        for (int mt = 0; mt < 4; ++mt) {
            bf16x8 afrag = __builtin_bit_cast(bf16x8, wq[(ch * 4 + mt) * 64 + lane]);
            acc[mt] = __builtin_amdgcn_mfma_f32_16x16x32_bf16(afrag, bfrag, acc[mt], 0, 0, 0);
        }
        if (ch + 1 < NCHUNK) produce(ch + 1);
    }

    // C/D layout: col = lane&15 (pixel), row = (lane>>4)*4 + reg (out channel)
    const int n = lane & 15, quad = lane >> 4;
    const int rem_out = rem_base + wave * 16 + n;
    float* outp = out + (size_t)b * COUT * HOWO + rem_out;
#pragma unroll
    for (int mt = 0; mt < 4; ++mt) {
#pragma unroll
        for (int r = 0; r < 4; ++r) {
            int o = mt * 16 + quad * 4 + r;
            outp[(size_t)o * HOWO] = acc[mt][r] + sbias[o];
        }
    }
}

extern "C" void kernel_launch(void* const* d_in, const int* in_sizes, int n_in,
                              void* d_out, int out_size, void* d_ws, size_t ws_size,
                              hipStream_t stream) {
    const float* x    = (const float*)d_in[0];
    const float* off  = (const float*)d_in[1];
    const float* wgt  = (const float*)d_in[2];
    const float* bias = (const float*)d_in[3];
    float* out = (float*)d_out;

    uint4* xh = (uint4*)d_ws;                             // 8,388,608 B
    uint4* wq = (uint4*)((char*)d_ws + 8388608);          // 73,728 B

    prep_x<<<dim3(BB * DGN * HWSZ / 256), dim3(256), 0, stream>>>(x, xh);
    prep_w<<<dim3(NCHUNK), dim3(256), 0, stream>>>(wgt, wq);
    dcn_mfma<<<dim3(BB * HO * WO / 64), dim3(256), 0, stream>>>(xh, off, wq, bias, out);
}